// Round 15
// baseline (211.526 us; speedup 1.0000x reference)
//
#include <hip/hip_runtime.h>
#include <hip/hip_bf16.h>
#include <math.h>

#define NN 20000
#define NE 320000
#define C0I 32
#define C1I 16
#define C0O 64
#define C1O 16
#define EPSF 1e-8f
#define STAGE_TOTAL 1671264   // total staged f32 elements
#define STAGE_V4    417816    // /4
#define RSTR 84               // LDS row stride (84 mod 32 = 20 -> 2-way max, free)
#define FGS  208              // FG row (16-aligned): aggA(48) | C(96, d*32+c) | x1agg(48) | pad | z@207

using bf16 = __hip_bfloat16;

__device__ __forceinline__ float bb2f(unsigned short u) {
    return __uint_as_float(((unsigned)u) << 16);
}

// wave-level LDS fence: drain outstanding ds ops + forbid compile-time motion
__device__ __forceinline__ void lds_fence() {
    asm volatile("s_waitcnt lgkmcnt(0)" ::: "memory");
    __builtin_amdgcn_sched_barrier(0);
}

// ---- kA: detect dtype + stage all float inputs as f32 + dst histogram ----
__global__ __launch_bounds__(256) void se3_convert(
    const void* s0, const void* s1, const void* s2, const void* s3,
    const void* s4, const void* s5, const void* s6, const void* s7,
    const void* s8, const void* s9, const void* s10, const void* s11,
    const int* __restrict__ ei,
    int* __restrict__ flag, float* __restrict__ dst, int* __restrict__ cnt) {
    __shared__ int sj;
    if (threadIdx.x == 0) sj = 0;
    __syncthreads();
    {   // f32 data read as bf16 at even indices shows junk exponents
        const unsigned short* p = (const unsigned short*)s0;
        bool junk = false;
        int i0 = threadIdx.x * 8;
#pragma unroll
        for (int k = 0; k < 4; ++k) {
            float v = bb2f(p[i0 + k * 2]);
            if (!(fabsf(v) < 1e3f)) junk = true;
        }
        if (junk) atomicOr(&sj, 1);
    }
    __syncthreads();
    int isf32 = sj;
    int gid = blockIdx.x * 256 + threadIdx.x;
    if (gid == 0) *flag = isf32;
    if (gid < NE) atomicAdd(&cnt[ei[NE + gid]], 1);   // histogram (cnt pre-zeroed)
    if (gid >= STAGE_V4) return;

    const void* src; int off;  // vec4 units
    if      (gid < 160000) { src = s0;  off = gid; }
    else if (gid < 400000) { src = s1;  off = gid - 160000; }
    else if (gid < 415000) { src = s2;  off = gid - 400000; }
    else if (gid < 415512) { src = s3;  off = gid - 415000; }
    else if (gid < 416024) { src = s4;  off = gid - 415512; }
    else if (gid < 416280) { src = s5;  off = gid - 416024; }
    else if (gid < 416792) { src = s6;  off = gid - 416280; }
    else if (gid < 417048) { src = s7;  off = gid - 416792; }
    else if (gid < 417176) { src = s8;  off = gid - 417048; }
    else if (gid < 417240) { src = s9;  off = gid - 417176; }
    else if (gid < 417752) { src = s10; off = gid - 417240; }
    else                   { src = s11; off = gid - 417752; }

    float4 v;
    if (isf32) {
        v = ((const float4*)src)[off];
    } else {
        ushort4 u = ((const ushort4*)src)[off];
        v = make_float4(bb2f(u.x), bb2f(u.y), bb2f(u.z), bb2f(u.w));
    }
    ((float4*)dst)[gid] = v;
}

// ---- kB: block 0: exclusive scan cnt -> rowptr,wptr; blocks 1-8: weight combines ----
__global__ __launch_bounds__(1024) void se3_scanw(
    const int* __restrict__ cnt, int* __restrict__ rowptr, int* __restrict__ wptr,
    const float* __restrict__ wq0, const float* __restrict__ wk00,
    const float* __restrict__ wk10,
    const float* __restrict__ wv00, const float* __restrict__ wv10,
    const float* __restrict__ wv01, const float* __restrict__ wv11,
    const float* __restrict__ ws0, const float* __restrict__ ws1,
    float* __restrict__ wqkc, float* __restrict__ M0cat, float* __restrict__ M1cat) {
    if (blockIdx.x == 0) {
        __shared__ int tmp[1024];
        int t = threadIdx.x;
        int base = t * 20;
        int v[20]; int s = 0;
#pragma unroll
        for (int i = 0; i < 20; ++i) {
            int idx = base + i;
            int c = (idx < NN) ? cnt[idx] : 0;
            v[i] = s; s += c;
        }
        tmp[t] = s;
        __syncthreads();
        for (int off = 1; off < 1024; off <<= 1) {
            int x = (t >= off) ? tmp[t - off] : 0;
            __syncthreads();
            tmp[t] += x;
            __syncthreads();
        }
        int tb = (t > 0) ? tmp[t - 1] : 0;
#pragma unroll
        for (int i = 0; i < 20; ++i) {
            int idx = base + i;
            if (idx < NN) { int r = tb + v[i]; rowptr[idx] = r; wptr[idx] = r; }
        }
        if (t == 1023) rowptr[NN] = NE;
    } else {
        int i = (blockIdx.x - 1) * 1024 + threadIdx.x;
        if (i < 1536) {
            int cp = i / 48, c = i % 48;
            float a = 0.f;
            if (c < 32) { for (int j = 0; j < C0O; ++j) a += wq0[cp*C0O+j] * wk00[c*C0O+j]; }
            else        { for (int j = 0; j < C0O; ++j) a += wq0[cp*C0O+j] * wk10[(c-32)*C0O+j]; }
            wqkc[i] = a;
        } else if (i < 1536 + 5120) {
            int k = i - 1536;
            int r = k >> 6, j = k & 63;
            M0cat[k] = (r < 32) ? wv00[r*64+j] : (r < 48) ? wv10[(r-32)*64+j] : ws0[(r-48)*64+j];
        } else if (i < 1536 + 5120 + 1024) {
            int k = i - 6656;
            int r = k >> 4, f = k & 15;
            M1cat[k] = (r < 16) ? wv11[r*16+f] : (r < 48) ? wv01[(r-16)*16+f] : ws1[(r-48)*16+f];
        }
    }
}

// ---- kC: blocks [0,1250): CSR scatter (src AND dst); blocks [1250,6250): qvec
//      (qvec part reads wqkc straight through L1 -- no per-block LDS staging) ----
__global__ __launch_bounds__(256) void se3_scatqv(
    const int* __restrict__ ei, int* __restrict__ wptr,
    int* __restrict__ csr_src, int* __restrict__ csr_dst,
    const float* __restrict__ x0, const float* __restrict__ wqkc,
    float* __restrict__ qvec) {
    int b = blockIdx.x;
    if (b < 1250) {
        int e = b * 256 + threadIdx.x;
        if (e < NE) {
            int d = ei[NE + e];
            int off = atomicAdd(&wptr[d], 1);
            csr_src[off] = ei[e];
            csr_dst[off] = d;
        }
    } else {
        int wv = threadIdx.x >> 6, lane = threadIdx.x & 63;
        int n = (b - 1250) * 4 + wv;
        float x0v = (lane < 32) ? x0[(size_t)n * 32 + lane] : 0.f;
        int li = (lane < 48) ? lane : 0;
        float qh = 0.f;
        for (int cp = 0; cp < 32; ++cp)
            qh += __shfl(x0v, cp) * wqkc[cp * 48 + li];
        if (lane < 48) qvec[(size_t)n * 48 + lane] = qh;
    }
}

// ---- kF: UNIFORM edge-window waves. Wave w handles CSR window [16w,16w+16).
//      No per-node loop; commutative softmax (exp without max-sub, clamped);
//      segment-flush via atomicAdd into FG. 20000 identical waves. ----
__global__ __launch_bounds__(256) void se3_fused(
    const float* __restrict__ x0, const float* __restrict__ x1,
    const float* __restrict__ pos, const float* __restrict__ qvec,
    const int* __restrict__ csr_src, const int* __restrict__ csr_dst,
    float* __restrict__ FG) {
    __shared__ __align__(16) float rows[4][16][RSTR];
    __shared__ __align__(16) float sW4[4][16][4];
    __shared__ int sdst[4][16];

    int tid = threadIdx.x, wv = tid >> 6, lane = tid & 63;
    float (*R)[RSTR] = rows[wv];
    float (*W4)[4] = sW4[wv];
    int* dstS = sdst[wv];
    int p0 = (blockIdx.x * 4 + wv) * 16;     // grid 5000 -> windows cover NE exactly
    int e4 = lane >> 2, j4 = lane & 3;
    int cc = (lane >= 32 && lane < 48) ? (lane - 32) : 0;

    // ---- stage: 4 lanes per edge (all 64 lanes active) ----
    int s_e = csr_src[p0 + e4];
    int d_e = csr_dst[p0 + e4];
    float rx = pos[d_e*3]   - pos[s_e*3];
    float ry = pos[d_e*3+1] - pos[s_e*3+1];
    float rz = pos[d_e*3+2] - pos[s_e*3+2];
    float inv = 1.f / (sqrtf(rx*rx + ry*ry + rz*rz) + EPSF);
    float Yx = rx*inv, Yy = ry*inv, Yz = rz*inv;
    {
        const float4* px0 = (const float4*)(x0 + (size_t)s_e * 32);
        *(float4*)&R[e4][j4*8]   = px0[j4*2];
        *(float4*)&R[e4][j4*8+4] = px0[j4*2+1];
        const float4* px1 = (const float4*)(x1 + (size_t)s_e * 48);
        *(float4*)&R[e4][32+j4*12]   = px1[j4*3];
        *(float4*)&R[e4][32+j4*12+4] = px1[j4*3+1];
        *(float4*)&R[e4][32+j4*12+8] = px1[j4*3+2];
        if (j4 == 0) dstS[e4] = d_e;
    }
    lds_fence();   // stage writes visible before cross-lane reads

    // ---- logits: lane (e4,j4) covers c = j4+4k; q gathered from qvec[d_e] ----
    float part = 0.f;
    {
        const float* qrow = qvec + (size_t)d_e * 48;
#pragma unroll
        for (int k = 0; k < 12; ++k) {
            int c = j4 + 4*k;
            float kv;
            if (c < 32) kv = R[e4][c];
            else {
                int c1 = c - 32;
                kv = R[e4][32+3*c1]*Yx + R[e4][32+3*c1+1]*Yy + R[e4][32+3*c1+2]*Yz;
            }
            part += kv * qrow[c];
        }
    }
    part += __shfl_xor(part, 1);
    part += __shfl_xor(part, 2);
    float lg = part * 0.125f;                     // 1/sqrt(64)
    float w = __expf(fminf(lg, 80.f));            // commutative softmax weight
    if (j4 == 0) *(float4*)&W4[e4][0] = make_float4(w, Yx, Yy, Yz);
    lds_fence();   // W4 writes visible before Phase-B reads

    // ---- Phase B: lane = feature; accumulate over window, flush per segment ----
    float aA = 0.f, aB = 0.f, Cx = 0.f, Cy = 0.f, Cz = 0.f, zacc = 0.f;
#pragma unroll 4
    for (int e = 0; e < 16; ++e) {
        float4 wy = *(const float4*)&W4[e][0];
        float we = wy.x, Y0 = wy.y, Y1 = wy.z, Y2 = wy.w;
        float x1v = (lane < 48) ? R[e][32 + lane] : 0.f;
        if (lane < 32) {
            float wx = we * R[e][lane];
            aA += wx; Cx += wx * Y0; Cy += wx * Y1; Cz += wx * Y2;
        } else if (lane < 48) {
            float xd = R[e][32+3*cc]*Y0 + R[e][32+3*cc+1]*Y1 + R[e][32+3*cc+2]*Y2;
            aA += we * xd;
        }
        aB += we * x1v;
        zacc += we;
        int de = dstS[e];
        int dn = (e < 15) ? dstS[e + 1] : -1;
        if (dn != de) {   // wave-uniform flush (CSR is dst-sorted -> runs)
            float* fg = FG + (size_t)de * FGS;
            if (lane < 48) {
                atomicAdd(&fg[lane], aA);
                atomicAdd(&fg[144 + lane], aB);
            }
            if (lane < 32) {
                atomicAdd(&fg[48 + lane], Cx);
                atomicAdd(&fg[80 + lane], Cy);
                atomicAdd(&fg[112 + lane], Cz);
            }
            if (lane == 48) atomicAdd(&fg[207], zacc);
            aA = 0.f; aB = 0.f; Cx = 0.f; Cy = 0.f; Cz = 0.f; zacc = 0.f;
        }
    }
}

// ---- kG: epilogue, wave-per-DUAL-node register/scratch form (round-13-proven).
//      No big LDS matrices: M0cat/M1cat rows broadcast-read from L2, one load
//      feeds both nodes. 2500 blocks x 4 waves x 2 nodes = NN. ----
__global__ __launch_bounds__(256) void se3_epi(
    const float* __restrict__ FG, const float* __restrict__ x0,
    const float* __restrict__ x1,
    const float* __restrict__ M0cat, const float* __restrict__ M1cat,
    const int* __restrict__ flag, void* __restrict__ out) {
    __shared__ float sc[4][2][288];
    int tid = threadIdx.x, wv = tid >> 6, lane = tid & 63;
    int nA = (blockIdx.x * 4 + wv) * 2, nB = nA + 1;
    float* swA = sc[wv][0];
    float* swB = sc[wv][1];
    const float* fgA = FG + (size_t)nA * FGS;
    const float* fgB = FG + (size_t)nB * FGS;
    float izA = 1.f / (fgA[207] + EPSF);
    float izB = 1.f / (fgB[207] + EPSF);
    // scratch layout (per node): [0-47] feat=[a0agg|dotagg]/z, [48-79] x0n,
    //   [96+3r+d]: r<16 x1agg/z, 16<=r<48 C[d][c]/z, r>=48 x1n
    if (lane < 48) {
        swA[lane]       = fgA[lane] * izA;        swB[lane]       = fgB[lane] * izB;
        swA[96 + lane]  = fgA[144 + lane] * izA;  swB[96 + lane]  = fgB[144 + lane] * izB;
        swA[240 + lane] = x1[(size_t)nA * 48 + lane];
        swB[240 + lane] = x1[(size_t)nB * 48 + lane];
    }
    if (lane < 32) {
        swA[48 + lane] = x0[(size_t)nA * 32 + lane];
        swB[48 + lane] = x0[(size_t)nB * 32 + lane];
        swA[144 + lane*3 + 0] = fgA[48 + lane] * izA;
        swA[144 + lane*3 + 1] = fgA[80 + lane] * izA;
        swA[144 + lane*3 + 2] = fgA[112 + lane] * izA;
        swB[144 + lane*3 + 0] = fgB[48 + lane] * izB;
        swB[144 + lane*3 + 1] = fgB[80 + lane] * izB;
        swB[144 + lane*3 + 2] = fgB[112 + lane] * izB;
    }
    lds_fence();   // scratch writes visible before cross-lane reads
    int isf32 = *flag;
    float o0A = 0.f, o0B = 0.f;
    for (int r = 0; r < 80; ++r) {
        float mv = M0cat[r * 64 + lane];     // one load feeds both nodes
        o0A += swA[r] * mv;
        o0B += swB[r] * mv;
    }
    int f = lane / 3, d = lane - 3 * f;
    float o1A = 0.f, o1B = 0.f;
    if (lane < 48) {
        for (int r = 0; r < 64; ++r) {
            float mv = M1cat[r * 16 + f];
            o1A += swA[96 + 3*r + d] * mv;
            o1B += swB[96 + 3*r + d] * mv;
        }
    }

    if (isf32) {
        ((float*)out)[(size_t)nA * 64 + lane] = o0A;
        ((float*)out)[(size_t)nB * 64 + lane] = o0B;
        if (lane < 48) {
            ((float*)out)[(size_t)NN * 64 + (size_t)nA * 48 + lane] = o1A;
            ((float*)out)[(size_t)NN * 64 + (size_t)nB * 48 + lane] = o1B;
        }
    } else {
        ((bf16*)out)[(size_t)nA * 64 + lane] = __float2bfloat16(o0A);
        ((bf16*)out)[(size_t)nB * 64 + lane] = __float2bfloat16(o0B);
        if (lane < 48) {
            ((bf16*)out)[(size_t)NN * 64 + (size_t)nA * 48 + lane] = __float2bfloat16(o1A);
            ((bf16*)out)[(size_t)NN * 64 + (size_t)nB * 48 + lane] = __float2bfloat16(o1B);
        }
    }
}

extern "C" void kernel_launch(void* const* d_in, const int* in_sizes, int n_in,
                              void* d_out, int out_size, void* d_ws, size_t ws_size,
                              hipStream_t stream) {
    const int* ei = (const int*)d_in[3];

    int* flag  = (int*)d_ws;
    float* ws  = (float*)d_ws + 16;
    float* x0f  = ws;                 // 640000
    float* x1f  = x0f + 640000;       // 960000
    float* posf = x1f + 960000;       // 60000
    float* wq0    = posf + 60000;     // 2048
    float* wk00   = wq0 + 2048;       // 2048
    float* wk10   = wk00 + 2048;      // 1024
    float* wv00   = wk10 + 1024;      // 2048
    float* wv10   = wv00 + 2048;      // 1024
    float* wv01   = wv10 + 1024;      // 512
    float* wv11   = wv01 + 512;       // 256
    float* wself0 = wv11 + 256;       // 2048
    float* wself1 = wself0 + 2048;    // 256
    float* wqkc  = ws + STAGE_TOTAL;          // 1536
    float* M0cat = wqkc + 1536;               // 5120
    float* M1cat = M0cat + 5120;              // 1024
    int* cnt     = (int*)(M1cat + 1024);      // NN
    int* rowptr  = cnt + NN;                  // NN+1
    int* wptr    = rowptr + NN + 1;           // NN
    int* csr_src = wptr + NN;                 // NE
    int* csr_dst = csr_src + NE;              // NE
    float* qvec  = (float*)(csr_dst + NE);    // NN*48
    float* FG    = qvec + (size_t)NN * 48;    // NN*208  (total ~30 MB)

    hipMemsetAsync(cnt, 0, NN * sizeof(int), stream);
    hipMemsetAsync(FG, 0, (size_t)NN * FGS * sizeof(float), stream);
    se3_convert<<<1633, 256, 0, stream>>>(d_in[0], d_in[1], d_in[2],
        d_in[4], d_in[5], d_in[6], d_in[7], d_in[8], d_in[9], d_in[10], d_in[11], d_in[12],
        ei, flag, ws, cnt);
    se3_scanw<<<9, 1024, 0, stream>>>(cnt, rowptr, wptr,
        wq0, wk00, wk10, wv00, wv10, wv01, wv11, wself0, wself1,
        wqkc, M0cat, M1cat);
    se3_scatqv<<<6250, 256, 0, stream>>>(ei, wptr, csr_src, csr_dst, x0f, wqkc, qvec);
    se3_fused<<<5000, 256, 0, stream>>>(x0f, x1f, posf, qvec, csr_src, csr_dst, FG);
    se3_epi<<<625 * 4, 256, 0, stream>>>(FG, x0f, x1f, M0cat, M1cat, flag, d_out);
}

// Round 16
// 183.145 us; speedup vs baseline: 1.1550x; 1.1550x over previous
//
#include <hip/hip_runtime.h>
#include <hip/hip_bf16.h>
#include <math.h>

#define NN 20000
#define NE 320000
#define C0I 32
#define C1I 16
#define C0O 64
#define C1O 16
#define EPSF 1e-8f
#define STAGE_TOTAL 1671264   // total staged f32 elements
#define STAGE_V4    417816    // /4
#define RSTR 84               // LDS row stride (84 mod 32 = 20 -> 2-way max, free)
#define FGS  208              // FG row (16-aligned): aggA(48) | C(96, d*32+c) | x1agg(48) | pad | z@207

using bf16 = __hip_bfloat16;

__device__ __forceinline__ float bb2f(unsigned short u) {
    return __uint_as_float(((unsigned)u) << 16);
}

// wave-level LDS fence: drain outstanding ds ops + forbid compile-time motion
__device__ __forceinline__ void lds_fence() {
    asm volatile("s_waitcnt lgkmcnt(0)" ::: "memory");
    __builtin_amdgcn_sched_barrier(0);
}

// ---- kA: detect dtype + stage all float inputs as f32 + dst histogram ----
__global__ __launch_bounds__(256) void se3_convert(
    const void* s0, const void* s1, const void* s2, const void* s3,
    const void* s4, const void* s5, const void* s6, const void* s7,
    const void* s8, const void* s9, const void* s10, const void* s11,
    const int* __restrict__ ei,
    int* __restrict__ flag, float* __restrict__ dst, int* __restrict__ cnt) {
    __shared__ int sj;
    if (threadIdx.x == 0) sj = 0;
    __syncthreads();
    {   // f32 data read as bf16 at even indices shows junk exponents
        const unsigned short* p = (const unsigned short*)s0;
        bool junk = false;
        int i0 = threadIdx.x * 8;
#pragma unroll
        for (int k = 0; k < 4; ++k) {
            float v = bb2f(p[i0 + k * 2]);
            if (!(fabsf(v) < 1e3f)) junk = true;
        }
        if (junk) atomicOr(&sj, 1);
    }
    __syncthreads();
    int isf32 = sj;
    int gid = blockIdx.x * 256 + threadIdx.x;
    if (gid == 0) *flag = isf32;
    if (gid < NE) atomicAdd(&cnt[ei[NE + gid]], 1);   // histogram (cnt pre-zeroed)
    if (gid >= STAGE_V4) return;

    const void* src; int off;  // vec4 units
    if      (gid < 160000) { src = s0;  off = gid; }
    else if (gid < 400000) { src = s1;  off = gid - 160000; }
    else if (gid < 415000) { src = s2;  off = gid - 400000; }
    else if (gid < 415512) { src = s3;  off = gid - 415000; }
    else if (gid < 416024) { src = s4;  off = gid - 415512; }
    else if (gid < 416280) { src = s5;  off = gid - 416024; }
    else if (gid < 416792) { src = s6;  off = gid - 416280; }
    else if (gid < 417048) { src = s7;  off = gid - 416792; }
    else if (gid < 417176) { src = s8;  off = gid - 417048; }
    else if (gid < 417240) { src = s9;  off = gid - 417176; }
    else if (gid < 417752) { src = s10; off = gid - 417240; }
    else                   { src = s11; off = gid - 417752; }

    float4 v;
    if (isf32) {
        v = ((const float4*)src)[off];
    } else {
        ushort4 u = ((const ushort4*)src)[off];
        v = make_float4(bb2f(u.x), bb2f(u.y), bb2f(u.z), bb2f(u.w));
    }
    ((float4*)dst)[gid] = v;
}

// ---- kB: block 0: exclusive scan cnt -> rowptr,wptr; blocks 1-8: weight combines ----
__global__ __launch_bounds__(1024) void se3_scanw(
    const int* __restrict__ cnt, int* __restrict__ rowptr, int* __restrict__ wptr,
    const float* __restrict__ wq0, const float* __restrict__ wk00,
    const float* __restrict__ wk10,
    const float* __restrict__ wv00, const float* __restrict__ wv10,
    const float* __restrict__ wv01, const float* __restrict__ wv11,
    const float* __restrict__ ws0, const float* __restrict__ ws1,
    float* __restrict__ wqkc, float* __restrict__ M0cat, float* __restrict__ M1cat) {
    if (blockIdx.x == 0) {
        __shared__ int tmp[1024];
        int t = threadIdx.x;
        int base = t * 20;
        int v[20]; int s = 0;
#pragma unroll
        for (int i = 0; i < 20; ++i) {
            int idx = base + i;
            int c = (idx < NN) ? cnt[idx] : 0;
            v[i] = s; s += c;
        }
        tmp[t] = s;
        __syncthreads();
        for (int off = 1; off < 1024; off <<= 1) {
            int x = (t >= off) ? tmp[t - off] : 0;
            __syncthreads();
            tmp[t] += x;
            __syncthreads();
        }
        int tb = (t > 0) ? tmp[t - 1] : 0;
#pragma unroll
        for (int i = 0; i < 20; ++i) {
            int idx = base + i;
            if (idx < NN) { int r = tb + v[i]; rowptr[idx] = r; wptr[idx] = r; }
        }
        if (t == 1023) rowptr[NN] = NE;
    } else {
        int i = (blockIdx.x - 1) * 1024 + threadIdx.x;
        if (i < 1536) {
            int cp = i / 48, c = i % 48;
            float a = 0.f;
            if (c < 32) { for (int j = 0; j < C0O; ++j) a += wq0[cp*C0O+j] * wk00[c*C0O+j]; }
            else        { for (int j = 0; j < C0O; ++j) a += wq0[cp*C0O+j] * wk10[(c-32)*C0O+j]; }
            wqkc[i] = a;
        } else if (i < 1536 + 5120) {
            int k = i - 1536;
            int r = k >> 6, j = k & 63;
            M0cat[k] = (r < 32) ? wv00[r*64+j] : (r < 48) ? wv10[(r-32)*64+j] : ws0[(r-48)*64+j];
        } else if (i < 1536 + 5120 + 1024) {
            int k = i - 6656;
            int r = k >> 4, f = k & 15;
            M1cat[k] = (r < 16) ? wv11[r*16+f] : (r < 48) ? wv01[(r-16)*16+f] : ws1[(r-48)*16+f];
        }
    }
}

// ---- kC: blocks [0,1250): CSR scatter (src AND dst); blocks [1250,6250): qvec ----
__global__ __launch_bounds__(256) void se3_scatqv(
    const int* __restrict__ ei, int* __restrict__ wptr,
    int* __restrict__ csr_src, int* __restrict__ csr_dst,
    const float* __restrict__ x0, const float* __restrict__ wqkc,
    float* __restrict__ qvec) {
    int b = blockIdx.x;
    if (b < 1250) {
        int e = b * 256 + threadIdx.x;
        if (e < NE) {
            int d = ei[NE + e];
            int off = atomicAdd(&wptr[d], 1);
            csr_src[off] = ei[e];
            csr_dst[off] = d;
        }
    } else {
        int wv = threadIdx.x >> 6, lane = threadIdx.x & 63;
        int n = (b - 1250) * 4 + wv;
        float x0v = (lane < 32) ? x0[(size_t)n * 32 + lane] : 0.f;
        int li = (lane < 48) ? lane : 0;
        float qh = 0.f;
        for (int cp = 0; cp < 32; ++cp)
            qh += __shfl(x0v, cp) * wqkc[cp * 48 + li];
        if (lane < 48) qvec[(size_t)n * 48 + lane] = qh;
    }
}

// ---- kF: UNIFORM edge-window waves. Wave w handles CSR window [16w,16w+16).
//      Commutative softmax (exp without max-sub, clamped); segment-flush via
//      atomicAdd into FG. 20000 identical waves. ----
__global__ __launch_bounds__(256) void se3_fused(
    const float* __restrict__ x0, const float* __restrict__ x1,
    const float* __restrict__ pos, const float* __restrict__ qvec,
    const int* __restrict__ csr_src, const int* __restrict__ csr_dst,
    float* __restrict__ FG) {
    __shared__ __align__(16) float rows[4][16][RSTR];
    __shared__ __align__(16) float sW4[4][16][4];
    __shared__ int sdst[4][16];

    int tid = threadIdx.x, wv = tid >> 6, lane = tid & 63;
    float (*R)[RSTR] = rows[wv];
    float (*W4)[4] = sW4[wv];
    int* dstS = sdst[wv];
    int p0 = (blockIdx.x * 4 + wv) * 16;     // grid 5000 -> windows cover NE exactly
    int e4 = lane >> 2, j4 = lane & 3;
    int cc = (lane >= 32 && lane < 48) ? (lane - 32) : 0;

    // ---- stage: 4 lanes per edge (all 64 lanes active) ----
    int s_e = csr_src[p0 + e4];
    int d_e = csr_dst[p0 + e4];
    float rx = pos[d_e*3]   - pos[s_e*3];
    float ry = pos[d_e*3+1] - pos[s_e*3+1];
    float rz = pos[d_e*3+2] - pos[s_e*3+2];
    float inv = 1.f / (sqrtf(rx*rx + ry*ry + rz*rz) + EPSF);
    float Yx = rx*inv, Yy = ry*inv, Yz = rz*inv;
    {
        const float4* px0 = (const float4*)(x0 + (size_t)s_e * 32);
        *(float4*)&R[e4][j4*8]   = px0[j4*2];
        *(float4*)&R[e4][j4*8+4] = px0[j4*2+1];
        const float4* px1 = (const float4*)(x1 + (size_t)s_e * 48);
        *(float4*)&R[e4][32+j4*12]   = px1[j4*3];
        *(float4*)&R[e4][32+j4*12+4] = px1[j4*3+1];
        *(float4*)&R[e4][32+j4*12+8] = px1[j4*3+2];
        if (j4 == 0) dstS[e4] = d_e;
    }
    lds_fence();   // stage writes visible before cross-lane reads

    // ---- logits: lane (e4,j4) covers c = j4+4k; q gathered from qvec[d_e] ----
    float part = 0.f;
    {
        const float* qrow = qvec + (size_t)d_e * 48;
#pragma unroll
        for (int k = 0; k < 12; ++k) {
            int c = j4 + 4*k;
            float kv;
            if (c < 32) kv = R[e4][c];
            else {
                int c1 = c - 32;
                kv = R[e4][32+3*c1]*Yx + R[e4][32+3*c1+1]*Yy + R[e4][32+3*c1+2]*Yz;
            }
            part += kv * qrow[c];
        }
    }
    part += __shfl_xor(part, 1);
    part += __shfl_xor(part, 2);
    float lg = part * 0.125f;                     // 1/sqrt(64)
    float w = __expf(fminf(lg, 80.f));            // commutative softmax weight
    if (j4 == 0) *(float4*)&W4[e4][0] = make_float4(w, Yx, Yy, Yz);
    lds_fence();   // W4 writes visible before Phase-B reads

    // ---- Phase B: lane = feature; accumulate over window, flush per segment ----
    float aA = 0.f, aB = 0.f, Cx = 0.f, Cy = 0.f, Cz = 0.f, zacc = 0.f;
#pragma unroll 4
    for (int e = 0; e < 16; ++e) {
        float4 wy = *(const float4*)&W4[e][0];
        float we = wy.x, Y0 = wy.y, Y1 = wy.z, Y2 = wy.w;
        float x1v = (lane < 48) ? R[e][32 + lane] : 0.f;
        if (lane < 32) {
            float wx = we * R[e][lane];
            aA += wx; Cx += wx * Y0; Cy += wx * Y1; Cz += wx * Y2;
        } else if (lane < 48) {
            float xd = R[e][32+3*cc]*Y0 + R[e][32+3*cc+1]*Y1 + R[e][32+3*cc+2]*Y2;
            aA += we * xd;
        }
        aB += we * x1v;
        zacc += we;
        int de = dstS[e];
        int dn = (e < 15) ? dstS[e + 1] : -1;
        if (dn != de) {   // wave-uniform flush (CSR is dst-sorted -> runs)
            float* fg = FG + (size_t)de * FGS;
            if (lane < 48) {
                atomicAdd(&fg[lane], aA);
                atomicAdd(&fg[144 + lane], aB);
            }
            if (lane < 32) {
                atomicAdd(&fg[48 + lane], Cx);
                atomicAdd(&fg[80 + lane], Cy);
                atomicAdd(&fg[112 + lane], Cz);
            }
            if (lane == 48) atomicAdd(&fg[207], zacc);
            aA = 0.f; aB = 0.f; Cx = 0.f; Cy = 0.f; Cz = 0.f; zacc = 0.f;
        }
    }
}

// ---- kG: epilogue HYBRID: matrices staged in LDS ONCE per block (24.6 KB,
//      coalesced flat), then each wave runs 4 dual-node scratch epilogues
//      from LDS only — no L2 loads in the hot loop (round 15's 144 L2
//      broadcast loads/wave were the 75us latency chain). 625 blocks x 4
//      waves x 4 iters x 2 nodes = NN exactly. ----
__global__ __launch_bounds__(256) void se3_epi(
    const float* __restrict__ FG, const float* __restrict__ x0,
    const float* __restrict__ x1,
    const float* __restrict__ M0cat, const float* __restrict__ M1cat,
    const int* __restrict__ flag, void* __restrict__ out) {
    __shared__ float sM0[5120];        // [r][j] flat, r<80, j<64
    __shared__ float sM1[1024];        // [r][f] flat, r<64, f<16
    __shared__ float sc[4][2][288];
    int tid = threadIdx.x, wv = tid >> 6, lane = tid & 63;
    for (int i = tid; i < 5120; i += 256) sM0[i] = M0cat[i];
    for (int i = tid; i < 1024; i += 256) sM1[i] = M1cat[i];
    __syncthreads();
    int isf32 = *flag;
    float* swA = sc[wv][0];
    float* swB = sc[wv][1];
    int f = lane / 3, d = lane - 3 * f;

    for (int it = 0; it < 4; ++it) {
        int pair = (blockIdx.x * 4 + wv) * 4 + it;
        int nA = pair * 2, nB = nA + 1;
        const float* fgA = FG + (size_t)nA * FGS;
        const float* fgB = FG + (size_t)nB * FGS;
        float izA = 1.f / (fgA[207] + EPSF);
        float izB = 1.f / (fgB[207] + EPSF);
        // scratch: [0-47] feat=[a0agg|dotagg]/z, [48-79] x0n,
        //   [96+3r+d]: r<16 x1agg/z, 16<=r<48 C[d][c]/z, r>=48 x1n
        if (lane < 48) {
            swA[lane]       = fgA[lane] * izA;        swB[lane]       = fgB[lane] * izB;
            swA[96 + lane]  = fgA[144 + lane] * izA;  swB[96 + lane]  = fgB[144 + lane] * izB;
            swA[240 + lane] = x1[(size_t)nA * 48 + lane];
            swB[240 + lane] = x1[(size_t)nB * 48 + lane];
        }
        if (lane < 32) {
            swA[48 + lane] = x0[(size_t)nA * 32 + lane];
            swB[48 + lane] = x0[(size_t)nB * 32 + lane];
            swA[144 + lane*3 + 0] = fgA[48 + lane] * izA;
            swA[144 + lane*3 + 1] = fgA[80 + lane] * izA;
            swA[144 + lane*3 + 2] = fgA[112 + lane] * izA;
            swB[144 + lane*3 + 0] = fgB[48 + lane] * izB;
            swB[144 + lane*3 + 1] = fgB[80 + lane] * izB;
            swB[144 + lane*3 + 2] = fgB[112 + lane] * izB;
        }
        lds_fence();   // scratch writes visible before cross-lane reads
        float o0A = 0.f, o0B = 0.f;
        for (int r = 0; r < 80; ++r) {
            float mv = sM0[r * 64 + lane];   // LDS, 2-way alias (free)
            o0A += swA[r] * mv;              // broadcast reads (free)
            o0B += swB[r] * mv;
        }
        float o1A = 0.f, o1B = 0.f;
        if (lane < 48) {
            for (int r = 0; r < 64; ++r) {
                float mv = sM1[r * 16 + f];
                o1A += swA[96 + 3*r + d] * mv;
                o1B += swB[96 + 3*r + d] * mv;
            }
        }

        if (isf32) {
            ((float*)out)[(size_t)nA * 64 + lane] = o0A;
            ((float*)out)[(size_t)nB * 64 + lane] = o0B;
            if (lane < 48) {
                ((float*)out)[(size_t)NN * 64 + (size_t)nA * 48 + lane] = o1A;
                ((float*)out)[(size_t)NN * 64 + (size_t)nB * 48 + lane] = o1B;
            }
        } else {
            ((bf16*)out)[(size_t)nA * 64 + lane] = __float2bfloat16(o0A);
            ((bf16*)out)[(size_t)nB * 64 + lane] = __float2bfloat16(o0B);
            if (lane < 48) {
                ((bf16*)out)[(size_t)NN * 64 + (size_t)nA * 48 + lane] = __float2bfloat16(o1A);
                ((bf16*)out)[(size_t)NN * 64 + (size_t)nB * 48 + lane] = __float2bfloat16(o1B);
            }
        }
        lds_fence();   // epilogue reads done before next iter overwrites scratch
    }
}

extern "C" void kernel_launch(void* const* d_in, const int* in_sizes, int n_in,
                              void* d_out, int out_size, void* d_ws, size_t ws_size,
                              hipStream_t stream) {
    const int* ei = (const int*)d_in[3];

    int* flag  = (int*)d_ws;
    float* ws  = (float*)d_ws + 16;
    float* x0f  = ws;                 // 640000
    float* x1f  = x0f + 640000;       // 960000
    float* posf = x1f + 960000;       // 60000
    float* wq0    = posf + 60000;     // 2048
    float* wk00   = wq0 + 2048;       // 2048
    float* wk10   = wk00 + 2048;      // 1024
    float* wv00   = wk10 + 1024;      // 2048
    float* wv10   = wv00 + 2048;      // 1024
    float* wv01   = wv10 + 1024;      // 512
    float* wv11   = wv01 + 512;       // 256
    float* wself0 = wv11 + 256;       // 2048
    float* wself1 = wself0 + 2048;    // 256
    float* wqkc  = ws + STAGE_TOTAL;          // 1536
    float* M0cat = wqkc + 1536;               // 5120
    float* M1cat = M0cat + 5120;              // 1024
    int* cnt     = (int*)(M1cat + 1024);      // NN
    int* rowptr  = cnt + NN;                  // NN+1
    int* wptr    = rowptr + NN + 1;           // NN
    int* csr_src = wptr + NN;                 // NE
    int* csr_dst = csr_src + NE;              // NE
    float* qvec  = (float*)(csr_dst + NE);    // NN*48
    float* FG    = qvec + (size_t)NN * 48;    // NN*208  (total ~30 MB)

    hipMemsetAsync(cnt, 0, NN * sizeof(int), stream);
    hipMemsetAsync(FG, 0, (size_t)NN * FGS * sizeof(float), stream);
    se3_convert<<<1633, 256, 0, stream>>>(d_in[0], d_in[1], d_in[2],
        d_in[4], d_in[5], d_in[6], d_in[7], d_in[8], d_in[9], d_in[10], d_in[11], d_in[12],
        ei, flag, ws, cnt);
    se3_scanw<<<9, 1024, 0, stream>>>(cnt, rowptr, wptr,
        wq0, wk00, wk10, wv00, wv10, wv01, wv11, wself0, wself1,
        wqkc, M0cat, M1cat);
    se3_scatqv<<<6250, 256, 0, stream>>>(ei, wptr, csr_src, csr_dst, x0f, wqkc, qvec);
    se3_fused<<<5000, 256, 0, stream>>>(x0f, x1f, posf, qvec, csr_src, csr_dst, FG);
    se3_epi<<<625, 256, 0, stream>>>(FG, x0f, x1f, M0cat, M1cat, flag, d_out);
}

// Round 17
// 175.326 us; speedup vs baseline: 1.2065x; 1.0446x over previous
//
#include <hip/hip_runtime.h>
#include <hip/hip_bf16.h>
#include <math.h>

#define NN 20000
#define NE 320000
#define EPSF 1e-8f
#define RSTR 84               // LDS row stride (84 mod 32 = 20 -> 2-way max, free)
#define FGS  208              // FG row (16-aligned): aggA(48) | C(96) | x1agg(48) | pad | z@207

using bf16 = __hip_bfloat16;

__device__ __forceinline__ float bb2f(unsigned short u) {
    return __uint_as_float(((unsigned)u) << 16);
}
// dtype-generic scalar weight load
__device__ __forceinline__ float ldw(const void* p, int i, int isf32) {
    return isf32 ? ((const float*)p)[i] : bb2f(((const unsigned short*)p)[i]);
}

// wave-level LDS fence: drain outstanding ds ops + forbid compile-time motion
__device__ __forceinline__ void lds_fence() {
    asm volatile("s_waitcnt lgkmcnt(0)" ::: "memory");
    __builtin_amdgcn_sched_barrier(0);
}

// ---- kA: detect dtype + flag + dst histogram + pos4 pack + weight combines
//      + (bf16 only) stage x0/x1 as f32. Grid 1280 x 256 = 327680 threads. ----
__global__ __launch_bounds__(256) void se3_convert(
    const void* x0r, const void* x1r, const void* posr,
    const void* wq0, const void* wk00, const void* wk10,
    const void* wv00, const void* wv10, const void* wv01, const void* wv11,
    const void* ws0, const void* ws1,
    const int* __restrict__ ei,
    int* __restrict__ flag, int* __restrict__ cnt,
    float* __restrict__ x0f, float* __restrict__ x1f,
    float* __restrict__ wqkc, float* __restrict__ M0cat, float* __restrict__ M1cat,
    float4* __restrict__ pos4) {
    __shared__ int sj;
    if (threadIdx.x == 0) sj = 0;
    __syncthreads();
    {   // f32 data read as bf16 at even indices shows junk exponents
        const unsigned short* p = (const unsigned short*)x0r;
        bool junk = false;
        int i0 = threadIdx.x * 8;
#pragma unroll
        for (int k = 0; k < 4; ++k) {
            float v = bb2f(p[i0 + k * 2]);
            if (!(fabsf(v) < 1e3f)) junk = true;
        }
        if (junk) atomicOr(&sj, 1);
    }
    __syncthreads();
    int isf32 = sj;
    int gid = blockIdx.x * 256 + threadIdx.x;
    if (gid == 0) *flag = isf32;
    if (gid < NE) atomicAdd(&cnt[ei[NE + gid]], 1);   // histogram (cnt pre-zeroed)
    if (gid < NN) {                                   // pos4 pack
        float px = ldw(posr, gid*3+0, isf32);
        float py = ldw(posr, gid*3+1, isf32);
        float pz = ldw(posr, gid*3+2, isf32);
        pos4[gid] = make_float4(px, py, pz, 0.f);
    }
    int ci = gid - NE;                                // combines: [0,7680)
    if (ci >= 0 && ci < 7680) {
        if (ci < 1536) {
            int cp = ci / 48, c = ci % 48;
            float a = 0.f;
            if (c < 32) { for (int j = 0; j < 64; ++j) a += ldw(wq0,cp*64+j,isf32)*ldw(wk00,c*64+j,isf32); }
            else        { for (int j = 0; j < 64; ++j) a += ldw(wq0,cp*64+j,isf32)*ldw(wk10,(c-32)*64+j,isf32); }
            wqkc[ci] = a;
        } else if (ci < 6656) {
            int k = ci - 1536; int r = k >> 6, j = k & 63;
            M0cat[k] = (r<32) ? ldw(wv00,r*64+j,isf32)
                     : (r<48) ? ldw(wv10,(r-32)*64+j,isf32) : ldw(ws0,(r-48)*64+j,isf32);
        } else {
            int k = ci - 6656; int r = k >> 4, f = k & 15;
            M1cat[k] = (r<16) ? ldw(wv11,r*16+f,isf32)
                     : (r<48) ? ldw(wv01,(r-16)*16+f,isf32) : ldw(ws1,(r-48)*16+f,isf32);
        }
    }
    if (!isf32) {   // stage x0 (160000 v4) + x1 (240000 v4) as f32, grid-stride
        for (int i = gid; i < 400000; i += 327680) {
            const ushort4* s; float4* dp; int off;
            if (i < 160000) { s = (const ushort4*)x0r; off = i;          dp = (float4*)x0f; }
            else            { s = (const ushort4*)x1r; off = i - 160000; dp = (float4*)x1f; }
            ushort4 u = s[off];
            dp[off] = make_float4(bb2f(u.x), bb2f(u.y), bb2f(u.z), bb2f(u.w));
        }
    }
}

// ---- kB: exclusive scan of cnt[NN] -> rowptr, wptr (1 block) ----
__global__ __launch_bounds__(1024) void se3_scan(
    const int* __restrict__ cnt, int* __restrict__ rowptr, int* __restrict__ wptr) {
    __shared__ int tmp[1024];
    int t = threadIdx.x;
    int base = t * 20;
    int v[20]; int s = 0;
#pragma unroll
    for (int i = 0; i < 20; ++i) {
        int idx = base + i;
        int c = (idx < NN) ? cnt[idx] : 0;
        v[i] = s; s += c;
    }
    tmp[t] = s;
    __syncthreads();
    for (int off = 1; off < 1024; off <<= 1) {
        int x = (t >= off) ? tmp[t - off] : 0;
        __syncthreads();
        tmp[t] += x;
        __syncthreads();
    }
    int tb = (t > 0) ? tmp[t - 1] : 0;
#pragma unroll
    for (int i = 0; i < 20; ++i) {
        int idx = base + i;
        if (idx < NN) { int r = tb + v[i]; rowptr[idx] = r; wptr[idx] = r; }
    }
    if (t == 1023) rowptr[NN] = NE;
}

// ---- kC: blocks [0,1250): CSR scatter (packed int2); blocks [1250,6250):
//      qvec (PERMUTED layout: q[(c&3)*12+(c>>2)]). All blocks: FG zeroing. ----
__global__ __launch_bounds__(256) void se3_scatqv(
    const int* __restrict__ ei, int* __restrict__ wptr,
    int2* __restrict__ csr,
    const void* x0r, const float* __restrict__ x0f,
    const float* __restrict__ wqkc,
    float* __restrict__ qvec, float* __restrict__ FG,
    const int* __restrict__ flag) {
    int b = blockIdx.x;
    int gid = b * 256 + threadIdx.x;
    if (gid < NN * FGS / 4) ((float4*)FG)[gid] = make_float4(0.f, 0.f, 0.f, 0.f);
    if (b < 1250) {
        if (gid < NE) {
            int d = ei[NE + gid];
            int off = atomicAdd(&wptr[d], 1);
            csr[off] = make_int2(ei[gid], d);
        }
    } else {
        int isf32 = *flag;
        int wv = threadIdx.x >> 6, lane = threadIdx.x & 63;
        int n = (b - 1250) * 4 + wv;
        float x0v = 0.f;
        if (lane < 32)
            x0v = isf32 ? ((const float*)x0r)[(size_t)n*32 + lane] : x0f[(size_t)n*32 + lane];
        int li = (lane < 48) ? lane : 0;
        float qh = 0.f;
        for (int cp = 0; cp < 32; ++cp)
            qh += __shfl(x0v, cp) * wqkc[cp * 48 + li];
        if (lane < 48) qvec[(size_t)n * 48 + (lane & 3) * 12 + (lane >> 2)] = qh;
    }
}

// ---- kF: UNIFORM edge-window waves (round-16-proven structure).
//      pos4 (2x16B gathers), permuted qvec (3xfloat4), packed csr (1x8B). ----
__global__ __launch_bounds__(256) void se3_fused(
    const void* x0r, const void* x1r,
    const float* __restrict__ x0f, const float* __restrict__ x1f,
    const float4* __restrict__ pos4, const float* __restrict__ qvec,
    const int2* __restrict__ csr, const int* __restrict__ flag,
    float* __restrict__ FG) {
    __shared__ __align__(16) float rows[4][16][RSTR];
    __shared__ __align__(16) float sW4[4][16][4];
    __shared__ int sdst[4][16];

    int tid = threadIdx.x, wv = tid >> 6, lane = tid & 63;
    int isf32 = *flag;
    const float* x0p = isf32 ? (const float*)x0r : x0f;
    const float* x1p = isf32 ? (const float*)x1r : x1f;
    float (*R)[RSTR] = rows[wv];
    float (*W4)[4] = sW4[wv];
    int* dstS = sdst[wv];
    int p0 = (blockIdx.x * 4 + wv) * 16;     // grid 5000 -> windows cover NE exactly
    int e4 = lane >> 2, j4 = lane & 3;
    int cc = (lane >= 32 && lane < 48) ? (lane - 32) : 0;

    // ---- stage: 4 lanes per edge ----
    int2 sd = csr[p0 + e4];
    int s_e = sd.x, d_e = sd.y;
    float4 pd = pos4[d_e], ps = pos4[s_e];
    float rx = pd.x - ps.x, ry = pd.y - ps.y, rz = pd.z - ps.z;
    float inv = 1.f / (sqrtf(rx*rx + ry*ry + rz*rz) + EPSF);
    float Yx = rx*inv, Yy = ry*inv, Yz = rz*inv;
    {
        const float4* px0 = (const float4*)(x0p + (size_t)s_e * 32);
        *(float4*)&R[e4][j4*8]   = px0[j4*2];
        *(float4*)&R[e4][j4*8+4] = px0[j4*2+1];
        const float4* px1 = (const float4*)(x1p + (size_t)s_e * 48);
        *(float4*)&R[e4][32+j4*12]   = px1[j4*3];
        *(float4*)&R[e4][32+j4*12+4] = px1[j4*3+1];
        *(float4*)&R[e4][32+j4*12+8] = px1[j4*3+2];
        if (j4 == 0) dstS[e4] = d_e;
    }
    lds_fence();   // stage writes visible before cross-lane reads

    // ---- logits: lane (e4,j4) covers c = j4+4k; q from permuted qvec ----
    float part = 0.f;
    {
        const float* qrow = qvec + (size_t)d_e * 48 + j4 * 12;
        float4 qa = *(const float4*)(qrow);
        float4 qb = *(const float4*)(qrow + 4);
        float4 qd = *(const float4*)(qrow + 8);
        float qk[12] = {qa.x,qa.y,qa.z,qa.w, qb.x,qb.y,qb.z,qb.w, qd.x,qd.y,qd.z,qd.w};
#pragma unroll
        for (int k = 0; k < 12; ++k) {
            int c = j4 + 4*k;
            float kv;
            if (c < 32) kv = R[e4][c];
            else {
                int c1 = c - 32;
                kv = R[e4][32+3*c1]*Yx + R[e4][32+3*c1+1]*Yy + R[e4][32+3*c1+2]*Yz;
            }
            part += kv * qk[k];
        }
    }
    part += __shfl_xor(part, 1);
    part += __shfl_xor(part, 2);
    float lg = part * 0.125f;                     // 1/sqrt(64)
    float w = __expf(fminf(lg, 80.f));            // commutative softmax weight
    if (j4 == 0) *(float4*)&W4[e4][0] = make_float4(w, Yx, Yy, Yz);
    lds_fence();   // W4 writes visible before Phase-B reads

    // ---- Phase B: lane = feature; accumulate over window, flush per segment ----
    float aA = 0.f, aB = 0.f, Cx = 0.f, Cy = 0.f, Cz = 0.f, zacc = 0.f;
#pragma unroll 4
    for (int e = 0; e < 16; ++e) {
        float4 wy = *(const float4*)&W4[e][0];
        float we = wy.x, Y0 = wy.y, Y1 = wy.z, Y2 = wy.w;
        float x1v = (lane < 48) ? R[e][32 + lane] : 0.f;
        if (lane < 32) {
            float wx = we * R[e][lane];
            aA += wx; Cx += wx * Y0; Cy += wx * Y1; Cz += wx * Y2;
        } else if (lane < 48) {
            float xd = R[e][32+3*cc]*Y0 + R[e][32+3*cc+1]*Y1 + R[e][32+3*cc+2]*Y2;
            aA += we * xd;
        }
        aB += we * x1v;
        zacc += we;
        int de = dstS[e];
        int dn = (e < 15) ? dstS[e + 1] : -1;
        if (dn != de) {   // wave-uniform flush (CSR is dst-sorted -> runs)
            float* fg = FG + (size_t)de * FGS;
            if (lane < 48) {
                atomicAdd(&fg[lane], aA);
                atomicAdd(&fg[144 + lane], aB);
            }
            if (lane < 32) {
                atomicAdd(&fg[48 + lane], Cx);
                atomicAdd(&fg[80 + lane], Cy);
                atomicAdd(&fg[112 + lane], Cz);
            }
            if (lane == 48) atomicAdd(&fg[207], zacc);
            aA = 0.f; aB = 0.f; Cx = 0.f; Cy = 0.f; Cz = 0.f; zacc = 0.f;
        }
    }
}

// ---- kG: epilogue hybrid (round-16-proven): matrices in LDS once/block;
//      4 waves x 4 iters x 2 nodes from LDS-only hot loop. ----
__global__ __launch_bounds__(256) void se3_epi(
    const float* __restrict__ FG,
    const void* x0r, const void* x1r,
    const float* __restrict__ x0f, const float* __restrict__ x1f,
    const float* __restrict__ M0cat, const float* __restrict__ M1cat,
    const int* __restrict__ flag, void* __restrict__ out) {
    __shared__ float sM0[5120];
    __shared__ float sM1[1024];
    __shared__ float sc[4][2][288];
    int tid = threadIdx.x, wv = tid >> 6, lane = tid & 63;
    for (int i = tid; i < 5120; i += 256) sM0[i] = M0cat[i];
    for (int i = tid; i < 1024; i += 256) sM1[i] = M1cat[i];
    __syncthreads();
    int isf32 = *flag;
    const float* x0p = isf32 ? (const float*)x0r : x0f;
    const float* x1p = isf32 ? (const float*)x1r : x1f;
    float* swA = sc[wv][0];
    float* swB = sc[wv][1];
    int f = lane / 3, d = lane - 3 * f;

    for (int it = 0; it < 4; ++it) {
        int pair = (blockIdx.x * 4 + wv) * 4 + it;
        int nA = pair * 2, nB = nA + 1;
        const float* fgA = FG + (size_t)nA * FGS;
        const float* fgB = FG + (size_t)nB * FGS;
        float izA = 1.f / (fgA[207] + EPSF);
        float izB = 1.f / (fgB[207] + EPSF);
        if (lane < 48) {
            swA[lane]       = fgA[lane] * izA;        swB[lane]       = fgB[lane] * izB;
            swA[96 + lane]  = fgA[144 + lane] * izA;  swB[96 + lane]  = fgB[144 + lane] * izB;
            swA[240 + lane] = x1p[(size_t)nA * 48 + lane];
            swB[240 + lane] = x1p[(size_t)nB * 48 + lane];
        }
        if (lane < 32) {
            swA[48 + lane] = x0p[(size_t)nA * 32 + lane];
            swB[48 + lane] = x0p[(size_t)nB * 32 + lane];
            swA[144 + lane*3 + 0] = fgA[48 + lane] * izA;
            swA[144 + lane*3 + 1] = fgA[80 + lane] * izA;
            swA[144 + lane*3 + 2] = fgA[112 + lane] * izA;
            swB[144 + lane*3 + 0] = fgB[48 + lane] * izB;
            swB[144 + lane*3 + 1] = fgB[80 + lane] * izB;
            swB[144 + lane*3 + 2] = fgB[112 + lane] * izB;
        }
        lds_fence();   // scratch writes visible before cross-lane reads
        float o0A = 0.f, o0B = 0.f;
        for (int r = 0; r < 80; ++r) {
            float mv = sM0[r * 64 + lane];
            o0A += swA[r] * mv;
            o0B += swB[r] * mv;
        }
        float o1A = 0.f, o1B = 0.f;
        if (lane < 48) {
            for (int r = 0; r < 64; ++r) {
                float mv = sM1[r * 16 + f];
                o1A += swA[96 + 3*r + d] * mv;
                o1B += swB[96 + 3*r + d] * mv;
            }
        }
        if (isf32) {
            ((float*)out)[(size_t)nA * 64 + lane] = o0A;
            ((float*)out)[(size_t)nB * 64 + lane] = o0B;
            if (lane < 48) {
                ((float*)out)[(size_t)NN * 64 + (size_t)nA * 48 + lane] = o1A;
                ((float*)out)[(size_t)NN * 64 + (size_t)nB * 48 + lane] = o1B;
            }
        } else {
            ((bf16*)out)[(size_t)nA * 64 + lane] = __float2bfloat16(o0A);
            ((bf16*)out)[(size_t)nB * 64 + lane] = __float2bfloat16(o0B);
            if (lane < 48) {
                ((bf16*)out)[(size_t)NN * 64 + (size_t)nA * 48 + lane] = __float2bfloat16(o1A);
                ((bf16*)out)[(size_t)NN * 64 + (size_t)nB * 48 + lane] = __float2bfloat16(o1B);
            }
        }
        lds_fence();   // epilogue reads done before next iter overwrites scratch
    }
}

extern "C" void kernel_launch(void* const* d_in, const int* in_sizes, int n_in,
                              void* d_out, int out_size, void* d_ws, size_t ws_size,
                              hipStream_t stream) {
    const int* ei = (const int*)d_in[3];

    int* flag  = (int*)d_ws;
    float* ws  = (float*)d_ws + 16;
    float* x0f   = ws;                        // 640000   (bf16 path only)
    float* x1f   = ws + 640000;               // 960000   (bf16 path only)
    float* wqkc  = ws + 1600000;              // 1536
    float* M0cat = ws + 1601536;              // 5120
    float* M1cat = ws + 1606656;              // 1024
    float4* pos4 = (float4*)(ws + 1607680);   // NN*4 = 80000
    int* cnt     = (int*)(ws + 1687680);      // 20000
    int* rowptr  = (int*)(ws + 1707680);      // 20004 (padded)
    int* wptr    = (int*)(ws + 1727684);      // 20000
    int2* csr    = (int2*)(ws + 1747684);     // NE int2 = 640000 ints
    float* qvec  = ws + 2387684;              // NN*48 = 960000
    float* FG    = ws + 3347684;              // NN*208 = 4160000  (total ~30 MB)

    hipMemsetAsync(cnt, 0, NN * sizeof(int), stream);
    se3_convert<<<1280, 256, 0, stream>>>(d_in[0], d_in[1], d_in[2],
        d_in[4], d_in[5], d_in[6], d_in[7], d_in[8], d_in[9], d_in[10], d_in[11], d_in[12],
        ei, flag, cnt, x0f, x1f, wqkc, M0cat, M1cat, pos4);
    se3_scan<<<1, 1024, 0, stream>>>(cnt, rowptr, wptr);
    se3_scatqv<<<6250, 256, 0, stream>>>(ei, wptr, csr, d_in[0], x0f, wqkc, qvec, FG, flag);
    se3_fused<<<5000, 256, 0, stream>>>(d_in[0], d_in[1], x0f, x1f, pos4, qvec, csr, flag, FG);
    se3_epi<<<625, 256, 0, stream>>>(FG, d_in[0], d_in[1], x0f, x1f, M0cat, M1cat, flag, d_out);
}

// Round 18
// 162.761 us; speedup vs baseline: 1.2996x; 1.0772x over previous
//
#include <hip/hip_runtime.h>
#include <hip/hip_bf16.h>
#include <math.h>

#define NN 20000
#define NE 320000
#define EPSF 1e-8f
#define RSTR 84               // LDS row stride (84 mod 32 = 20 -> 2-way max, free)
#define FGS  208              // FG row (16-aligned): aggA(48) | C(96) | x1agg(48) | pad | z@207

using bf16 = __hip_bfloat16;

__device__ __forceinline__ float bb2f(unsigned short u) {
    return __uint_as_float(((unsigned)u) << 16);
}
// dtype-generic scalar weight load
__device__ __forceinline__ float ldw(const void* p, int i, int isf32) {
    return isf32 ? ((const float*)p)[i] : bb2f(((const unsigned short*)p)[i]);
}

// wave-level LDS fence: drain outstanding ds ops + forbid compile-time motion
__device__ __forceinline__ void lds_fence() {
    asm volatile("s_waitcnt lgkmcnt(0)" ::: "memory");
    __builtin_amdgcn_sched_barrier(0);
}

// ---- kA: detect dtype + flag + dst histogram + pos4 pack + weight combines
//      + stage x0/x1 as f32 ALWAYS (f32: plain copy) so downstream kernels
//      never carry runtime dtype pointer-selects (r17: VGPR bloat in epi). ----
__global__ __launch_bounds__(256) void se3_convert(
    const void* x0r, const void* x1r, const void* posr,
    const void* wq0, const void* wk00, const void* wk10,
    const void* wv00, const void* wv10, const void* wv01, const void* wv11,
    const void* ws0, const void* ws1,
    const int* __restrict__ ei,
    int* __restrict__ flag, int* __restrict__ cnt,
    float* __restrict__ x0f, float* __restrict__ x1f,
    float* __restrict__ wqkc, float* __restrict__ M0cat, float* __restrict__ M1cat,
    float4* __restrict__ pos4) {
    __shared__ int sj;
    if (threadIdx.x == 0) sj = 0;
    __syncthreads();
    {   // f32 data read as bf16 at even indices shows junk exponents
        const unsigned short* p = (const unsigned short*)x0r;
        bool junk = false;
        int i0 = threadIdx.x * 8;
#pragma unroll
        for (int k = 0; k < 4; ++k) {
            float v = bb2f(p[i0 + k * 2]);
            if (!(fabsf(v) < 1e3f)) junk = true;
        }
        if (junk) atomicOr(&sj, 1);
    }
    __syncthreads();
    int isf32 = sj;
    int gid = blockIdx.x * 256 + threadIdx.x;
    if (gid == 0) *flag = isf32;
    if (gid < NE) atomicAdd(&cnt[ei[NE + gid]], 1);   // histogram (cnt pre-zeroed)
    if (gid < NN) {                                   // pos4 pack
        float px = ldw(posr, gid*3+0, isf32);
        float py = ldw(posr, gid*3+1, isf32);
        float pz = ldw(posr, gid*3+2, isf32);
        pos4[gid] = make_float4(px, py, pz, 0.f);
    }
    int ci = gid - NE;                                // combines: [0,7680)
    if (ci >= 0 && ci < 7680) {
        if (ci < 1536) {
            int cp = ci / 48, c = ci % 48;
            float a = 0.f;
            if (c < 32) { for (int j = 0; j < 64; ++j) a += ldw(wq0,cp*64+j,isf32)*ldw(wk00,c*64+j,isf32); }
            else        { for (int j = 0; j < 64; ++j) a += ldw(wq0,cp*64+j,isf32)*ldw(wk10,(c-32)*64+j,isf32); }
            wqkc[ci] = a;
        } else if (ci < 6656) {
            int k = ci - 1536; int r = k >> 6, j = k & 63;
            M0cat[k] = (r<32) ? ldw(wv00,r*64+j,isf32)
                     : (r<48) ? ldw(wv10,(r-32)*64+j,isf32) : ldw(ws0,(r-48)*64+j,isf32);
        } else {
            int k = ci - 6656; int r = k >> 4, f = k & 15;
            M1cat[k] = (r<16) ? ldw(wv11,r*16+f,isf32)
                     : (r<48) ? ldw(wv01,(r-16)*16+f,isf32) : ldw(ws1,(r-48)*16+f,isf32);
        }
    }
    // stage x0 (160000 v4) + x1 (240000 v4) as f32, grid-stride, both dtypes
    for (int i = gid; i < 400000; i += 327680) {
        const void* s; float4* dp; int off;
        if (i < 160000) { s = x0r; off = i;          dp = (float4*)x0f; }
        else            { s = x1r; off = i - 160000; dp = (float4*)x1f; }
        float4 v;
        if (isf32) {
            v = ((const float4*)s)[off];
        } else {
            ushort4 u = ((const ushort4*)s)[off];
            v = make_float4(bb2f(u.x), bb2f(u.y), bb2f(u.z), bb2f(u.w));
        }
        dp[off] = v;
    }
}

// ---- kB: exclusive scan of cnt[NN] -> wptr (1 block) ----
__global__ __launch_bounds__(1024) void se3_scan(
    const int* __restrict__ cnt, int* __restrict__ wptr) {
    __shared__ int tmp[1024];
    int t = threadIdx.x;
    int base = t * 20;
    int v[20]; int s = 0;
#pragma unroll
    for (int i = 0; i < 20; ++i) {
        int idx = base + i;
        int c = (idx < NN) ? cnt[idx] : 0;
        v[i] = s; s += c;
    }
    tmp[t] = s;
    __syncthreads();
    for (int off = 1; off < 1024; off <<= 1) {
        int x = (t >= off) ? tmp[t - off] : 0;
        __syncthreads();
        tmp[t] += x;
        __syncthreads();
    }
    int tb = (t > 0) ? tmp[t - 1] : 0;
#pragma unroll
    for (int i = 0; i < 20; ++i) {
        int idx = base + i;
        if (idx < NN) wptr[idx] = tb + v[i];
    }
}

// ---- kC: blocks [0,1250): CSR scatter (packed int2); blocks [1250,6250):
//      qvec (PERMUTED: q[(c&3)*12+(c>>2)], staged x0f). All blocks: FG zero. ----
__global__ __launch_bounds__(256) void se3_scatqv(
    const int* __restrict__ ei, int* __restrict__ wptr,
    int2* __restrict__ csr,
    const float* __restrict__ x0f, const float* __restrict__ wqkc,
    float* __restrict__ qvec, float* __restrict__ FG) {
    int b = blockIdx.x;
    int gid = b * 256 + threadIdx.x;
    if (gid < NN * FGS / 4) ((float4*)FG)[gid] = make_float4(0.f, 0.f, 0.f, 0.f);
    if (b < 1250) {
        if (gid < NE) {
            int d = ei[NE + gid];
            int off = atomicAdd(&wptr[d], 1);
            csr[off] = make_int2(ei[gid], d);
        }
    } else {
        int wv = threadIdx.x >> 6, lane = threadIdx.x & 63;
        int n = (b - 1250) * 4 + wv;
        float x0v = (lane < 32) ? x0f[(size_t)n * 32 + lane] : 0.f;
        int li = (lane < 48) ? lane : 0;
        float qh = 0.f;
        for (int cp = 0; cp < 32; ++cp)
            qh += __shfl(x0v, cp) * wqkc[cp * 48 + li];
        if (lane < 48) qvec[(size_t)n * 48 + (lane & 3) * 12 + (lane >> 2)] = qh;
    }
}

// ---- kF: UNIFORM edge-window waves (proven structure). Staged pointers only.
//      pos4 (2x16B), permuted qvec (3xfloat4), packed csr (1x8B). ----
__global__ __launch_bounds__(256) void se3_fused(
    const float* __restrict__ x0p, const float* __restrict__ x1p,
    const float4* __restrict__ pos4, const float* __restrict__ qvec,
    const int2* __restrict__ csr, float* __restrict__ FG) {
    __shared__ __align__(16) float rows[4][16][RSTR];
    __shared__ __align__(16) float sW4[4][16][4];
    __shared__ int sdst[4][16];

    int tid = threadIdx.x, wv = tid >> 6, lane = tid & 63;
    float (*R)[RSTR] = rows[wv];
    float (*W4)[4] = sW4[wv];
    int* dstS = sdst[wv];
    int p0 = (blockIdx.x * 4 + wv) * 16;     // grid 5000 -> windows cover NE exactly
    int e4 = lane >> 2, j4 = lane & 3;
    int cc = (lane >= 32 && lane < 48) ? (lane - 32) : 0;

    // ---- stage: 4 lanes per edge ----
    int2 sd = csr[p0 + e4];
    int s_e = sd.x, d_e = sd.y;
    float4 pd = pos4[d_e], ps = pos4[s_e];
    float rx = pd.x - ps.x, ry = pd.y - ps.y, rz = pd.z - ps.z;
    float inv = 1.f / (sqrtf(rx*rx + ry*ry + rz*rz) + EPSF);
    float Yx = rx*inv, Yy = ry*inv, Yz = rz*inv;
    {
        const float4* px0 = (const float4*)(x0p + (size_t)s_e * 32);
        *(float4*)&R[e4][j4*8]   = px0[j4*2];
        *(float4*)&R[e4][j4*8+4] = px0[j4*2+1];
        const float4* px1 = (const float4*)(x1p + (size_t)s_e * 48);
        *(float4*)&R[e4][32+j4*12]   = px1[j4*3];
        *(float4*)&R[e4][32+j4*12+4] = px1[j4*3+1];
        *(float4*)&R[e4][32+j4*12+8] = px1[j4*3+2];
        if (j4 == 0) dstS[e4] = d_e;
    }
    lds_fence();   // stage writes visible before cross-lane reads

    // ---- logits: lane (e4,j4) covers c = j4+4k; q from permuted qvec ----
    float part = 0.f;
    {
        const float* qrow = qvec + (size_t)d_e * 48 + j4 * 12;
        float4 qa = *(const float4*)(qrow);
        float4 qb = *(const float4*)(qrow + 4);
        float4 qd = *(const float4*)(qrow + 8);
        float qk[12] = {qa.x,qa.y,qa.z,qa.w, qb.x,qb.y,qb.z,qb.w, qd.x,qd.y,qd.z,qd.w};
#pragma unroll
        for (int k = 0; k < 12; ++k) {
            int c = j4 + 4*k;
            float kv;
            if (c < 32) kv = R[e4][c];
            else {
                int c1 = c - 32;
                kv = R[e4][32+3*c1]*Yx + R[e4][32+3*c1+1]*Yy + R[e4][32+3*c1+2]*Yz;
            }
            part += kv * qk[k];
        }
    }
    part += __shfl_xor(part, 1);
    part += __shfl_xor(part, 2);
    float lg = part * 0.125f;                     // 1/sqrt(64)
    float w = __expf(fminf(lg, 80.f));            // commutative softmax weight
    if (j4 == 0) *(float4*)&W4[e4][0] = make_float4(w, Yx, Yy, Yz);
    lds_fence();   // W4 writes visible before Phase-B reads

    // ---- Phase B: lane = feature; accumulate over window, flush per segment ----
    float aA = 0.f, aB = 0.f, Cx = 0.f, Cy = 0.f, Cz = 0.f, zacc = 0.f;
#pragma unroll 4
    for (int e = 0; e < 16; ++e) {
        float4 wy = *(const float4*)&W4[e][0];
        float we = wy.x, Y0 = wy.y, Y1 = wy.z, Y2 = wy.w;
        float x1v = (lane < 48) ? R[e][32 + lane] : 0.f;
        if (lane < 32) {
            float wx = we * R[e][lane];
            aA += wx; Cx += wx * Y0; Cy += wx * Y1; Cz += wx * Y2;
        } else if (lane < 48) {
            float xd = R[e][32+3*cc]*Y0 + R[e][32+3*cc+1]*Y1 + R[e][32+3*cc+2]*Y2;
            aA += we * xd;
        }
        aB += we * x1v;
        zacc += we;
        int de = dstS[e];
        int dn = (e < 15) ? dstS[e + 1] : -1;
        if (dn != de) {   // wave-uniform flush (CSR is dst-sorted -> runs)
            float* fg = FG + (size_t)de * FGS;
            if (lane < 48) {
                atomicAdd(&fg[lane], aA);
                atomicAdd(&fg[144 + lane], aB);
            }
            if (lane < 32) {
                atomicAdd(&fg[48 + lane], Cx);
                atomicAdd(&fg[80 + lane], Cy);
                atomicAdd(&fg[112 + lane], Cz);
            }
            if (lane == 48) atomicAdd(&fg[207], zacc);
            aA = 0.f; aB = 0.f; Cx = 0.f; Cy = 0.f; Cz = 0.f; zacc = 0.f;
        }
    }
}

// ---- kG: epilogue hybrid, ONE dual-node iteration per wave, 2500 blocks
//      (r17: 625 blocks x 4 iters -> 2.4 blocks/CU straggling + VGPR 184).
//      Matrices in LDS once/block; hot loop LDS-only; staged pointers only. ----
__global__ __launch_bounds__(256) void se3_epi(
    const float* __restrict__ FG,
    const float* __restrict__ x0p, const float* __restrict__ x1p,
    const float* __restrict__ M0cat, const float* __restrict__ M1cat,
    const int* __restrict__ flag, void* __restrict__ out) {
    __shared__ float sM0[5120];
    __shared__ float sM1[1024];
    __shared__ float sc[4][2][288];
    int tid = threadIdx.x, wv = tid >> 6, lane = tid & 63;
    for (int i = tid; i < 5120; i += 256) sM0[i] = M0cat[i];
    for (int i = tid; i < 1024; i += 256) sM1[i] = M1cat[i];
    __syncthreads();
    int isf32 = *flag;
    float* swA = sc[wv][0];
    float* swB = sc[wv][1];
    int f = lane / 3, d = lane - 3 * f;

    int pair = blockIdx.x * 4 + wv;          // grid 2500 -> 10000 pairs = NN nodes
    int nA = pair * 2, nB = nA + 1;
    const float* fgA = FG + (size_t)nA * FGS;
    const float* fgB = FG + (size_t)nB * FGS;
    float izA = 1.f / (fgA[207] + EPSF);
    float izB = 1.f / (fgB[207] + EPSF);
    // scratch: [0-47] feat=[a0agg|dotagg]/z, [48-79] x0n,
    //   [96+3r+d]: r<16 x1agg/z, 16<=r<48 C[d][c]/z, r>=48 x1n
    if (lane < 48) {
        swA[lane]       = fgA[lane] * izA;        swB[lane]       = fgB[lane] * izB;
        swA[96 + lane]  = fgA[144 + lane] * izA;  swB[96 + lane]  = fgB[144 + lane] * izB;
        swA[240 + lane] = x1p[(size_t)nA * 48 + lane];
        swB[240 + lane] = x1p[(size_t)nB * 48 + lane];
    }
    if (lane < 32) {
        swA[48 + lane] = x0p[(size_t)nA * 32 + lane];
        swB[48 + lane] = x0p[(size_t)nB * 32 + lane];
        swA[144 + lane*3 + 0] = fgA[48 + lane] * izA;
        swA[144 + lane*3 + 1] = fgA[80 + lane] * izA;
        swA[144 + lane*3 + 2] = fgA[112 + lane] * izA;
        swB[144 + lane*3 + 0] = fgB[48 + lane] * izB;
        swB[144 + lane*3 + 1] = fgB[80 + lane] * izB;
        swB[144 + lane*3 + 2] = fgB[112 + lane] * izB;
    }
    lds_fence();   // scratch writes visible before cross-lane reads
    float o0A = 0.f, o0B = 0.f;
    for (int r = 0; r < 80; ++r) {
        float mv = sM0[r * 64 + lane];       // LDS, 2-way alias (free)
        o0A += swA[r] * mv;                  // broadcast reads (free)
        o0B += swB[r] * mv;
    }
    float o1A = 0.f, o1B = 0.f;
    if (lane < 48) {
        for (int r = 0; r < 64; ++r) {
            float mv = sM1[r * 16 + f];
            o1A += swA[96 + 3*r + d] * mv;
            o1B += swB[96 + 3*r + d] * mv;
        }
    }
    if (isf32) {
        ((float*)out)[(size_t)nA * 64 + lane] = o0A;
        ((float*)out)[(size_t)nB * 64 + lane] = o0B;
        if (lane < 48) {
            ((float*)out)[(size_t)NN * 64 + (size_t)nA * 48 + lane] = o1A;
            ((float*)out)[(size_t)NN * 64 + (size_t)nB * 48 + lane] = o1B;
        }
    } else {
        ((bf16*)out)[(size_t)nA * 64 + lane] = __float2bfloat16(o0A);
        ((bf16*)out)[(size_t)nB * 64 + lane] = __float2bfloat16(o0B);
        if (lane < 48) {
            ((bf16*)out)[(size_t)NN * 64 + (size_t)nA * 48 + lane] = __float2bfloat16(o1A);
            ((bf16*)out)[(size_t)NN * 64 + (size_t)nB * 48 + lane] = __float2bfloat16(o1B);
        }
    }
}

extern "C" void kernel_launch(void* const* d_in, const int* in_sizes, int n_in,
                              void* d_out, int out_size, void* d_ws, size_t ws_size,
                              hipStream_t stream) {
    const int* ei = (const int*)d_in[3];

    int* flag  = (int*)d_ws;
    float* ws  = (float*)d_ws + 16;
    float* x0f   = ws;                        // 640000
    float* x1f   = ws + 640000;               // 960000
    float* wqkc  = ws + 1600000;              // 1536
    float* M0cat = ws + 1601536;              // 5120
    float* M1cat = ws + 1606656;              // 1024
    float4* pos4 = (float4*)(ws + 1607680);   // NN*4 = 80000
    int* cnt     = (int*)(ws + 1687680);      // 20000
    int* wptr    = (int*)(ws + 1707680);      // 20000
    int2* csr    = (int2*)(ws + 1727680);     // NE int2 = 640000 ints
    float* qvec  = ws + 2367680;              // NN*48 = 960000
    float* FG    = ws + 3327680;              // NN*208 = 4160000  (total ~30 MB)

    hipMemsetAsync(cnt, 0, NN * sizeof(int), stream);
    se3_convert<<<1280, 256, 0, stream>>>(d_in[0], d_in[1], d_in[2],
        d_in[4], d_in[5], d_in[6], d_in[7], d_in[8], d_in[9], d_in[10], d_in[11], d_in[12],
        ei, flag, cnt, x0f, x1f, wqkc, M0cat, M1cat, pos4);
    se3_scan<<<1, 1024, 0, stream>>>(cnt, wptr);
    se3_scatqv<<<6250, 256, 0, stream>>>(ei, wptr, csr, x0f, wqkc, qvec, FG);
    se3_fused<<<5000, 256, 0, stream>>>(x0f, x1f, pos4, qvec, csr, FG);
    se3_epi<<<2500, 256, 0, stream>>>(FG, x0f, x1f, M0cat, M1cat, flag, d_out);
}

// Round 20
// 154.062 us; speedup vs baseline: 1.3730x; 1.0565x over previous
//
#include <hip/hip_runtime.h>
#include <hip/hip_bf16.h>
#include <math.h>

#define NN 20000
#define NE 320000
#define EPSF 1e-8f
#define RSTR 84               // LDS row stride (84 mod 32 = 20 -> 2-way max, free)
#define FGS  208              // FG row (16-aligned): aggA(48) | C(96) | x1agg(48) | pad | z@207

using bf16 = __hip_bfloat16;

__device__ __forceinline__ float bb2f(unsigned short u) {
    return __uint_as_float(((unsigned)u) << 16);
}
// dtype-generic scalar weight load
__device__ __forceinline__ float ldw(const void* p, int i, int isf32) {
    return isf32 ? ((const float*)p)[i] : bb2f(((const unsigned short*)p)[i]);
}

// wave-level LDS fence: drain outstanding ds ops + forbid compile-time motion
__device__ __forceinline__ void lds_fence() {
    asm volatile("s_waitcnt lgkmcnt(0)" ::: "memory");
    __builtin_amdgcn_sched_barrier(0);
}

// ---- kA: detect dtype + flag + dst histogram + pos4 pack + weight combines
//      + stage x0/x1 as f32 always. ----
__global__ __launch_bounds__(256) void se3_convert(
    const void* x0r, const void* x1r, const void* posr,
    const void* wq0, const void* wk00, const void* wk10,
    const void* wv00, const void* wv10, const void* wv01, const void* wv11,
    const void* ws0, const void* ws1,
    const int* __restrict__ ei,
    int* __restrict__ flag, int* __restrict__ cnt,
    float* __restrict__ x0f, float* __restrict__ x1f,
    float* __restrict__ wqkc, float* __restrict__ M0cat, float* __restrict__ M1cat,
    float4* __restrict__ pos4) {
    __shared__ int sj;
    if (threadIdx.x == 0) sj = 0;
    __syncthreads();
    {   // f32 data read as bf16 at even indices shows junk exponents
        const unsigned short* p = (const unsigned short*)x0r;
        bool junk = false;
        int i0 = threadIdx.x * 8;
#pragma unroll
        for (int k = 0; k < 4; ++k) {
            float v = bb2f(p[i0 + k * 2]);
            if (!(fabsf(v) < 1e3f)) junk = true;
        }
        if (junk) atomicOr(&sj, 1);
    }
    __syncthreads();
    int isf32 = sj;
    int gid = blockIdx.x * 256 + threadIdx.x;
    if (gid == 0) *flag = isf32;
    if (gid < NE) atomicAdd(&cnt[ei[NE + gid]], 1);   // histogram (cnt pre-zeroed)
    if (gid < NN) {                                   // pos4 pack
        float px = ldw(posr, gid*3+0, isf32);
        float py = ldw(posr, gid*3+1, isf32);
        float pz = ldw(posr, gid*3+2, isf32);
        pos4[gid] = make_float4(px, py, pz, 0.f);
    }
    int ci = gid - NE;                                // combines: [0,7680)
    if (ci >= 0 && ci < 7680) {
        if (ci < 1536) {
            int cp = ci / 48, c = ci % 48;
            float a = 0.f;
            if (c < 32) { for (int j = 0; j < 64; ++j) a += ldw(wq0,cp*64+j,isf32)*ldw(wk00,c*64+j,isf32); }
            else        { for (int j = 0; j < 64; ++j) a += ldw(wq0,cp*64+j,isf32)*ldw(wk10,(c-32)*64+j,isf32); }
            wqkc[ci] = a;
        } else if (ci < 6656) {
            int k = ci - 1536; int r = k >> 6, j = k & 63;
            M0cat[k] = (r<32) ? ldw(wv00,r*64+j,isf32)
                     : (r<48) ? ldw(wv10,(r-32)*64+j,isf32) : ldw(ws0,(r-48)*64+j,isf32);
        } else {
            int k = ci - 6656; int r = k >> 4, f = k & 15;
            M1cat[k] = (r<16) ? ldw(wv11,r*16+f,isf32)
                     : (r<48) ? ldw(wv01,(r-16)*16+f,isf32) : ldw(ws1,(r-48)*16+f,isf32);
        }
    }
    // stage x0 (160000 v4) + x1 (240000 v4) as f32, grid-stride, both dtypes
    for (int i = gid; i < 400000; i += 327680) {
        const void* s; float4* dp; int off;
        if (i < 160000) { s = x0r; off = i;          dp = (float4*)x0f; }
        else            { s = x1r; off = i - 160000; dp = (float4*)x1f; }
        float4 v;
        if (isf32) {
            v = ((const float4*)s)[off];
        } else {
            ushort4 u = ((const ushort4*)s)[off];
            v = make_float4(bb2f(u.x), bb2f(u.y), bb2f(u.z), bb2f(u.w));
        }
        dp[off] = v;
    }
}

// ---- kB: exclusive scan of cnt[NN] -> wptr (1 block) ----
__global__ __launch_bounds__(1024) void se3_scan(
    const int* __restrict__ cnt, int* __restrict__ wptr) {
    __shared__ int tmp[1024];
    int t = threadIdx.x;
    int base = t * 20;
    int v[20]; int s = 0;
#pragma unroll
    for (int i = 0; i < 20; ++i) {
        int idx = base + i;
        int c = (idx < NN) ? cnt[idx] : 0;
        v[i] = s; s += c;
    }
    tmp[t] = s;
    __syncthreads();
    for (int off = 1; off < 1024; off <<= 1) {
        int x = (t >= off) ? tmp[t - off] : 0;
        __syncthreads();
        tmp[t] += x;
        __syncthreads();
    }
    int tb = (t > 0) ? tmp[t - 1] : 0;
#pragma unroll
    for (int i = 0; i < 20; ++i) {
        int idx = base + i;
        if (idx < NN) wptr[idx] = tb + v[i];
    }
}

// ---- kC: blocks [0,1250): CSR scatter (packed int2); blocks [1250,6250):
//      qvec (PERMUTED: q[(c&3)*12+(c>>2)]). All blocks: FG zeroing. ----
__global__ __launch_bounds__(256) void se3_scatqv(
    const int* __restrict__ ei, int* __restrict__ wptr,
    int2* __restrict__ csr,
    const float* __restrict__ x0f, const float* __restrict__ wqkc,
    float* __restrict__ qvec, float* __restrict__ FG) {
    int b = blockIdx.x;
    int gid = b * 256 + threadIdx.x;
    if (gid < NN * FGS / 4) ((float4*)FG)[gid] = make_float4(0.f, 0.f, 0.f, 0.f);
    if (b < 1250) {
        if (gid < NE) {
            int d = ei[NE + gid];
            int off = atomicAdd(&wptr[d], 1);
            csr[off] = make_int2(ei[gid], d);
        }
    } else {
        int wv = threadIdx.x >> 6, lane = threadIdx.x & 63;
        int n = (b - 1250) * 4 + wv;
        float x0v = (lane < 32) ? x0f[(size_t)n * 32 + lane] : 0.f;
        int li = (lane < 48) ? lane : 0;
        float qh = 0.f;
        for (int cp = 0; cp < 32; ++cp)
            qh += __shfl(x0v, cp) * wqkc[cp * 48 + li];
        if (lane < 48) qvec[(size_t)n * 48 + (lane & 3) * 12 + (lane >> 2)] = qh;
    }
}

// ---- kF: UNIFORM edge-window waves (proven structure). ----
__global__ __launch_bounds__(256) void se3_fused(
    const float* __restrict__ x0p, const float* __restrict__ x1p,
    const float4* __restrict__ pos4, const float* __restrict__ qvec,
    const int2* __restrict__ csr, float* __restrict__ FG) {
    __shared__ __align__(16) float rows[4][16][RSTR];
    __shared__ __align__(16) float sW4[4][16][4];
    __shared__ int sdst[4][16];

    int tid = threadIdx.x, wv = tid >> 6, lane = tid & 63;
    float (*R)[RSTR] = rows[wv];
    float (*W4)[4] = sW4[wv];
    int* dstS = sdst[wv];
    int p0 = (blockIdx.x * 4 + wv) * 16;     // grid 5000 -> windows cover NE exactly
    int e4 = lane >> 2, j4 = lane & 3;
    int cc = (lane >= 32 && lane < 48) ? (lane - 32) : 0;

    // ---- stage: 4 lanes per edge ----
    int2 sd = csr[p0 + e4];
    int s_e = sd.x, d_e = sd.y;
    float4 pd = pos4[d_e], ps = pos4[s_e];
    float rx = pd.x - ps.x, ry = pd.y - ps.y, rz = pd.z - ps.z;
    float inv = 1.f / (sqrtf(rx*rx + ry*ry + rz*rz) + EPSF);
    float Yx = rx*inv, Yy = ry*inv, Yz = rz*inv;
    {
        const float4* px0 = (const float4*)(x0p + (size_t)s_e * 32);
        *(float4*)&R[e4][j4*8]   = px0[j4*2];
        *(float4*)&R[e4][j4*8+4] = px0[j4*2+1];
        const float4* px1 = (const float4*)(x1p + (size_t)s_e * 48);
        *(float4*)&R[e4][32+j4*12]   = px1[j4*3];
        *(float4*)&R[e4][32+j4*12+4] = px1[j4*3+1];
        *(float4*)&R[e4][32+j4*12+8] = px1[j4*3+2];
        if (j4 == 0) dstS[e4] = d_e;
    }
    lds_fence();   // stage writes visible before cross-lane reads

    // ---- logits: lane (e4,j4) covers c = j4+4k; q from permuted qvec ----
    float part = 0.f;
    {
        const float* qrow = qvec + (size_t)d_e * 48 + j4 * 12;
        float4 qa = *(const float4*)(qrow);
        float4 qb = *(const float4*)(qrow + 4);
        float4 qd = *(const float4*)(qrow + 8);
        float qk[12] = {qa.x,qa.y,qa.z,qa.w, qb.x,qb.y,qb.z,qb.w, qd.x,qd.y,qd.z,qd.w};
#pragma unroll
        for (int k = 0; k < 12; ++k) {
            int c = j4 + 4*k;
            float kv;
            if (c < 32) kv = R[e4][c];
            else {
                int c1 = c - 32;
                kv = R[e4][32+3*c1]*Yx + R[e4][32+3*c1+1]*Yy + R[e4][32+3*c1+2]*Yz;
            }
            part += kv * qk[k];
        }
    }
    part += __shfl_xor(part, 1);
    part += __shfl_xor(part, 2);
    float lg = part * 0.125f;                     // 1/sqrt(64)
    float w = __expf(fminf(lg, 80.f));            // commutative softmax weight
    if (j4 == 0) *(float4*)&W4[e4][0] = make_float4(w, Yx, Yy, Yz);
    lds_fence();   // W4 writes visible before Phase-B reads

    // ---- Phase B: lane = feature; accumulate over window, flush per segment ----
    float aA = 0.f, aB = 0.f, Cx = 0.f, Cy = 0.f, Cz = 0.f, zacc = 0.f;
#pragma unroll 4
    for (int e = 0; e < 16; ++e) {
        float4 wy = *(const float4*)&W4[e][0];
        float we = wy.x, Y0 = wy.y, Y1 = wy.z, Y2 = wy.w;
        float x1v = (lane < 48) ? R[e][32 + lane] : 0.f;
        if (lane < 32) {
            float wx = we * R[e][lane];
            aA += wx; Cx += wx * Y0; Cy += wx * Y1; Cz += wx * Y2;
        } else if (lane < 48) {
            float xd = R[e][32+3*cc]*Y0 + R[e][32+3*cc+1]*Y1 + R[e][32+3*cc+2]*Y2;
            aA += we * xd;
        }
        aB += we * x1v;
        zacc += we;
        int de = dstS[e];
        int dn = (e < 15) ? dstS[e + 1] : -1;
        if (dn != de) {   // wave-uniform flush (CSR is dst-sorted -> runs)
            float* fg = FG + (size_t)de * FGS;
            if (lane < 48) {
                atomicAdd(&fg[lane], aA);
                atomicAdd(&fg[144 + lane], aB);
            }
            if (lane < 32) {
                atomicAdd(&fg[48 + lane], Cx);
                atomicAdd(&fg[80 + lane], Cy);
                atomicAdd(&fg[112 + lane], Cz);
            }
            if (lane == 48) atomicAdd(&fg[207], zacc);
            aA = 0.f; aB = 0.f; Cx = 0.f; Cy = 0.f; Cz = 0.f; zacc = 0.f;
        }
    }
}

// ---- kG: epilogue v3 — matrix-column-in-REGISTERS, zero LDS.
//      Waves 0..9999: out0 (2 nodes each); waves 10000..19999: out1.
//      REQUIRES grid 5000 x 256 (20000 waves) — r19 launched 2500 and the
//      out1 branch never ran. ----
__global__ __launch_bounds__(256) void se3_epi(
    const float* __restrict__ FG,
    const float* __restrict__ x0p, const float* __restrict__ x1p,
    const float* __restrict__ M0cat, const float* __restrict__ M1cat,
    const int* __restrict__ flag, void* __restrict__ out) {
    int tid = threadIdx.x, wv = tid >> 6, lane = tid & 63;
    int w = blockIdx.x * 4 + wv;
    int isf32 = *flag;
    if (w < 10000) {
        // ---- out0: o0[j] = iz*sum_{r<48} fg[r]*M0[r][j] + sum_{r<32} x0n[r]*M0[48+r][j]
        float M[80];
#pragma unroll
        for (int r = 0; r < 80; ++r) M[r] = M0cat[r * 64 + lane];
#pragma unroll
        for (int t = 0; t < 2; ++t) {
            int n = w * 2 + t;
            const float* fg = FG + (size_t)n * FGS;
            float iz = 1.f / (fg[207] + EPSF);
            float a1 = 0.f;
#pragma unroll
            for (int r = 0; r < 48; ++r) a1 += fg[r] * M[r];          // uniform loads
            float a2 = 0.f;
            const float* x0n = x0p + (size_t)n * 32;
#pragma unroll
            for (int r = 0; r < 32; ++r) a2 += x0n[r] * M[48 + r];    // uniform loads
            float o0 = a1 * iz + a2;
            if (isf32) ((float*)out)[(size_t)n * 64 + lane] = o0;
            else       ((bf16*)out)[(size_t)n * 64 + lane] = __float2bfloat16(o0);
        }
    } else {
        // ---- out1: lane = f*3+d (lane<48);
        //      o1 = iz*( sum_{r<16} fg[144+3r+d]*M1[r][f]
        //              + sum_{16<=r<48} fg[48+d*32+(r-16)]*M1[r][f] )
        //         + sum_{r>=48} x1n[3(r-48)+d]*M1[r][f]
        int f = lane / 3, d = lane - 3 * f;
        bool act = lane < 48;
        float M[64];
#pragma unroll
        for (int r = 0; r < 64; ++r) M[r] = act ? M1cat[r * 16 + f] : 0.f;
#pragma unroll
        for (int t = 0; t < 2; ++t) {
            int n = (w - 10000) * 2 + t;
            const float* fg = FG + (size_t)n * FGS;
            float iz = 1.f / (fg[207] + EPSF);
            float a1 = 0.f;
            if (act) {
#pragma unroll
                for (int r = 0; r < 16; ++r) a1 += fg[144 + 3*r + d] * M[r];
#pragma unroll
                for (int r = 16; r < 48; ++r) a1 += fg[48 + d*32 + (r - 16)] * M[r];
            }
            float a2 = 0.f;
            const float* x1n = x1p + (size_t)n * 48;
            if (act) {
#pragma unroll
                for (int r = 48; r < 64; ++r) a2 += x1n[3*(r - 48) + d] * M[r];
            }
            float o1 = a1 * iz + a2;
            if (act) {
                size_t o = (size_t)NN * 64 + (size_t)n * 48 + lane;
                if (isf32) ((float*)out)[o] = o1;
                else       ((bf16*)out)[o] = __float2bfloat16(o1);
            }
        }
    }
}

extern "C" void kernel_launch(void* const* d_in, const int* in_sizes, int n_in,
                              void* d_out, int out_size, void* d_ws, size_t ws_size,
                              hipStream_t stream) {
    const int* ei = (const int*)d_in[3];

    int* flag  = (int*)d_ws;
    float* ws  = (float*)d_ws + 16;
    float* x0f   = ws;                        // 640000
    float* x1f   = ws + 640000;               // 960000
    float* wqkc  = ws + 1600000;              // 1536
    float* M0cat = ws + 1601536;              // 5120
    float* M1cat = ws + 1606656;              // 1024
    float4* pos4 = (float4*)(ws + 1607680);   // NN*4 = 80000
    int* cnt     = (int*)(ws + 1687680);      // 20000
    int* wptr    = (int*)(ws + 1707680);      // 20000
    int2* csr    = (int2*)(ws + 1727680);     // NE int2 = 640000 ints
    float* qvec  = ws + 2367680;              // NN*48 = 960000
    float* FG    = ws + 3327680;              // NN*208 = 4160000  (total ~30 MB)

    hipMemsetAsync(cnt, 0, NN * sizeof(int), stream);
    se3_convert<<<1280, 256, 0, stream>>>(d_in[0], d_in[1], d_in[2],
        d_in[4], d_in[5], d_in[6], d_in[7], d_in[8], d_in[9], d_in[10], d_in[11], d_in[12],
        ei, flag, cnt, x0f, x1f, wqkc, M0cat, M1cat, pos4);
    se3_scan<<<1, 1024, 0, stream>>>(cnt, wptr);
    se3_scatqv<<<6250, 256, 0, stream>>>(ei, wptr, csr, x0f, wqkc, qvec, FG);
    se3_fused<<<5000, 256, 0, stream>>>(x0f, x1f, pos4, qvec, csr, FG);
    se3_epi<<<5000, 256, 0, stream>>>(FG, x0f, x1f, M0cat, M1cat, flag, d_out);
}